// Round 1
// baseline (14558.240 us; speedup 1.0000x reference)
//
#include <hip/hip_runtime.h>
#include <cstdint>
#include <cstddef>

typedef unsigned short u16;
typedef short bf16x8 __attribute__((ext_vector_type(8)));
typedef u16   u16x8  __attribute__((ext_vector_type(8)));
typedef float f32x4  __attribute__((ext_vector_type(4)));

#define NT  512
#define NB  64
#define NH  1024
#define NTB 32768   // NT*NB
#define G4  4096

#define AS1C(p) ((const __attribute__((address_space(1))) void*)(p))
#define AS3(p)  ((__attribute__((address_space(3))) void*)(p))

__device__ __forceinline__ float b2f(u16 u){
  return __uint_as_float(((unsigned)u) << 16);
}
__device__ __forceinline__ u16 f2b(float f){
  unsigned u = __float_as_uint(f);
  return (u16)((u + 0x7fffu + ((u >> 16) & 1u)) >> 16);
}

// ---------------- f32 -> bf16 conversion ----------------
__global__ void cvt_bf16(const float* __restrict__ in, u16* __restrict__ out, int n8){
  int stride = gridDim.x * blockDim.x;
  for (int i = blockIdx.x * blockDim.x + threadIdx.x; i < n8; i += stride){
    const float4* p = (const float4*)(in + (size_t)i * 8);
    float4 a = p[0], b = p[1];
    u16x8 r;
    r[0]=f2b(a.x); r[1]=f2b(a.y); r[2]=f2b(a.z); r[3]=f2b(a.w);
    r[4]=f2b(b.x); r[5]=f2b(b.y); r[6]=f2b(b.z); r[7]=f2b(b.w);
    *(u16x8*)(out + (size_t)i * 8) = r;
  }
}

// ---------------- z-gate precompute: z_pre[r] = x[r,:] . W_ih[4096,:] + bias ----------------
__global__ void zpre_kernel(const float* __restrict__ x, const float* __restrict__ Wih,
                            const float* __restrict__ b_ih, const float* __restrict__ b_hh,
                            float* __restrict__ zp){
  int gw   = (blockIdx.x * 256 + threadIdx.x) >> 6;
  int lane = threadIdx.x & 63;
  const float* wz = Wih + (size_t)4096 * 1024;
  float4 wv[4];
  #pragma unroll
  for (int j = 0; j < 4; ++j) wv[j] = *(const float4*)&wz[lane*16 + j*4];
  float bz = b_ih[4096] + b_hh[4096];
  for (int r = gw; r < NTB; r += 1024){
    const float* xr = x + (size_t)r * 1024 + lane * 16;
    float s = 0.f;
    #pragma unroll
    for (int j = 0; j < 4; ++j){
      float4 xv = *(const float4*)&xr[j*4];
      s += xv.x*wv[j].x + xv.y*wv[j].y + xv.z*wv[j].z + xv.w*wv[j].w;
    }
    #pragma unroll
    for (int o = 32; o > 0; o >>= 1) s += __shfl_down(s, o);
    if (lane == 0) zp[r] = s + bz;
  }
}

// ---------------- Phase-1 GEMM: gx[32768,4096] = Xb @ Wb^T + bias ----------------
template<typename GT>
__global__ __launch_bounds__(256, 2) void gemm_gx(
    const u16* __restrict__ Xb, const u16* __restrict__ Wb,
    const float* __restrict__ b_ih, const float* __restrict__ b_hh,
    GT* __restrict__ gx)
{
  __shared__ u16 As[128*32];
  __shared__ u16 Bs[128*32];
  const int tid  = threadIdx.x;
  const int lane = tid & 63, wave = tid >> 6;
  const int wr = wave >> 1, wc = wave & 1;
  const int m0 = (blockIdx.x & 255) * 128;
  const int n0 = (blockIdx.x >> 8) * 128;
  const int srow = wave * 16 + (lane >> 2);
  const int scol = (lane & 3) * 8;
  const u16* gA = Xb + (size_t)(m0 + srow) * 1024 + scol;
  const u16* gB = Wb + (size_t)(n0 + srow) * 1024 + scol;
  char* lA = (char*)As + wave * 1024;
  char* lB = (char*)Bs + wave * 1024;
  const int fr = lane & 15, fo = (lane >> 4) * 8;

  f32x4 acc[4][4] = {};
  for (int k0 = 0; k0 < 1024; k0 += 32){
    __syncthreads();
    __builtin_amdgcn_global_load_lds(AS1C(gA + k0),            AS3(lA),        16, 0, 0);
    __builtin_amdgcn_global_load_lds(AS1C(gA + 64*1024 + k0),  AS3(lA + 4096), 16, 0, 0);
    __builtin_amdgcn_global_load_lds(AS1C(gB + k0),            AS3(lB),        16, 0, 0);
    __builtin_amdgcn_global_load_lds(AS1C(gB + 64*1024 + k0),  AS3(lB + 4096), 16, 0, 0);
    __syncthreads();
    bf16x8 a[4], b[4];
    #pragma unroll
    for (int mi = 0; mi < 4; ++mi)
      a[mi] = *(const bf16x8*)&As[(wr*64 + mi*16 + fr)*32 + fo];
    #pragma unroll
    for (int ni = 0; ni < 4; ++ni)
      b[ni] = *(const bf16x8*)&Bs[(wc*64 + ni*16 + fr)*32 + fo];
    #pragma unroll
    for (int mi = 0; mi < 4; ++mi)
      #pragma unroll
      for (int ni = 0; ni < 4; ++ni)
        acc[mi][ni] = __builtin_amdgcn_mfma_f32_16x16x32_bf16(a[mi], b[ni], acc[mi][ni], 0, 0, 0);
  }
  const int orow = (lane >> 4) * 4, ocol = lane & 15;
  #pragma unroll
  for (int ni = 0; ni < 4; ++ni){
    const int g = n0 + wc*64 + ni*16 + ocol;
    const float bias = b_ih[g] + b_hh[g];
    #pragma unroll
    for (int mi = 0; mi < 4; ++mi){
      const size_t rb = (size_t)(m0 + wr*64 + mi*16 + orow);
      #pragma unroll
      for (int r = 0; r < 4; ++r){
        float v = acc[mi][ni][r] + bias;
        if constexpr (sizeof(GT) == 4)
          __builtin_nontemporal_store(v, (float*)gx + (rb + r)*G4 + g);
        else
          __builtin_nontemporal_store(f2b(v), (u16*)gx + (rb + r)*G4 + g);
      }
    }
  }
}

// ---------------- group barrier (64 WGs sharing one batch-group) ----------------
__device__ __forceinline__ void group_barrier(unsigned* cnt, unsigned* gen, unsigned members){
  __syncthreads();
  if (threadIdx.x == 0){
    __threadfence();
    unsigned g0   = __hip_atomic_load(gen, __ATOMIC_RELAXED, __HIP_MEMORY_SCOPE_AGENT);
    unsigned prev = __hip_atomic_fetch_add(cnt, 1u, __ATOMIC_ACQ_REL, __HIP_MEMORY_SCOPE_AGENT);
    if (prev == members - 1u){
      __hip_atomic_store(cnt, 0u, __ATOMIC_RELAXED, __HIP_MEMORY_SCOPE_AGENT);
      __hip_atomic_fetch_add(gen, 1u, __ATOMIC_RELEASE, __HIP_MEMORY_SCOPE_AGENT);
    } else {
      while (__hip_atomic_load(gen, __ATOMIC_RELAXED, __HIP_MEMORY_SCOPE_AGENT) == g0)
        __builtin_amdgcn_s_sleep(2);
    }
    __threadfence();
  }
  __syncthreads();
}

__device__ __forceinline__ float ld_gx(const float* p){ return __builtin_nontemporal_load(p); }
__device__ __forceinline__ float ld_gx(const u16* p){ return b2f(__builtin_nontemporal_load(p)); }

// ---------------- Phase-2 persistent scan ----------------
// 256 WGs x 256 thr. WG = (mb: batch-group of 16, hb: 16 hidden units).
// Wave w owns gate w; its W_hh slice lives in VGPRs (Bw[32]).
template<typename GT>
__global__ __launch_bounds__(256, 1) void hmlstm_scan(
    const u16* __restrict__ Whh, const GT* __restrict__ gx,
    const float* __restrict__ zpre, u16* __restrict__ h0, u16* __restrict__ h1,
    float* __restrict__ out, unsigned* __restrict__ bar)
{
  const int tid  = threadIdx.x;
  const int lane = tid & 63, wave = tid >> 6;
  const int wg = blockIdx.x;
  const int mb = wg >> 6, hb = wg & 63;
  const int fr = lane & 15, hi4 = lane >> 4;
  const int b_l = tid >> 4, h_l = tid & 15;      // combine mapping: 16x16 = 256 threads
  const int browg = mb*16 + b_l;

  __shared__ float glds[4][16][16];
  __shared__ float zsum[16];
  __shared__ u16 wz[1024];

  ((unsigned long long*)wz)[tid] = ((const unsigned long long*)(Whh + (size_t)4096*1024))[tid];

  // persistent W_hh fragments: gate row = wave*1024 + hb*16 + fr
  const int grow = wave*1024 + hb*16 + fr;
  bf16x8 Bw[32];
  #pragma unroll
  for (int kc = 0; kc < 32; ++kc)
    Bw[kc] = *(const bf16x8*)&Whh[(size_t)grow*1024 + kc*32 + hi4*8];

  // zero h0 (group covers rows mb*16..mb*16+15)
  h0[mb*16384 + hb*256 + tid] = 0;

  unsigned* cnt = bar + mb*64;
  unsigned* gen = bar + mb*64 + 16;
  float c_reg = 0.f;

  group_barrier(cnt, gen, 64);

  for (int t = 0; t < NT; ++t){
    const u16* hc = (t & 1) ? h1 : h0;
    u16*       hn = (t & 1) ? h0 : h1;

    // early-issue gx loads (consumed after GEMM; latency hidden under z + MFMA)
    float gxl[4];
    {
      const GT* gp = gx + ((size_t)t*64 + mb*16 + hi4*4)*G4 + wave*1024 + hb*16 + fr;
      #pragma unroll
      for (int r = 0; r < 4; ++r) gxl[r] = ld_gx(gp + (size_t)r*G4);
    }
    float zpc = zpre[t*64 + browg];

    // z partial: thread = (batch b_l, k-segment h_l of 64)
    {
      float zp = 0.f;
      const u16* hr = hc + (size_t)browg*1024 + h_l*64;
      #pragma unroll
      for (int j = 0; j < 8; ++j){
        bf16x8 hv = *(const bf16x8*)&hr[j*8];
        bf16x8 wv = *(const bf16x8*)&wz[h_l*64 + j*8];
        #pragma unroll
        for (int e = 0; e < 8; ++e)
          zp += b2f((u16)hv[e]) * b2f((u16)wv[e]);
      }
      #pragma unroll
      for (int o = 8; o > 0; o >>= 1) zp += __shfl_xor(zp, o, 16);
      if (h_l == 0) zsum[b_l] = zp;
    }

    // recurrent GEMM: 16x16 tile (16 batches x 16 gate cols), K = 1024
    f32x4 ac0 = {}, ac1 = {}, ac2 = {}, ac3 = {};
    const u16* ha = hc + (size_t)(mb*16 + fr)*1024 + hi4*8;
    #pragma unroll
    for (int kc = 0; kc < 32; kc += 4){
      bf16x8 a0 = *(const bf16x8*)&ha[(kc+0)*32];
      bf16x8 a1 = *(const bf16x8*)&ha[(kc+1)*32];
      bf16x8 a2 = *(const bf16x8*)&ha[(kc+2)*32];
      bf16x8 a3 = *(const bf16x8*)&ha[(kc+3)*32];
      ac0 = __builtin_amdgcn_mfma_f32_16x16x32_bf16(a0, Bw[kc+0], ac0, 0, 0, 0);
      ac1 = __builtin_amdgcn_mfma_f32_16x16x32_bf16(a1, Bw[kc+1], ac1, 0, 0, 0);
      ac2 = __builtin_amdgcn_mfma_f32_16x16x32_bf16(a2, Bw[kc+2], ac2, 0, 0, 0);
      ac3 = __builtin_amdgcn_mfma_f32_16x16x32_bf16(a3, Bw[kc+3], ac3, 0, 0, 0);
    }
    f32x4 ac = (ac0 + ac1) + (ac2 + ac3);

    // gates -> LDS (wave 2 = tanh, others sigmoid)
    #pragma unroll
    for (int r = 0; r < 4; ++r){
      float v = ac[r] + gxl[r];
      float s = (wave == 2) ? (2.f/(1.f + __expf(-2.f*v)) - 1.f)
                            : (1.f/(1.f + __expf(-v)));
      glds[wave][hi4*4 + r][fr] = s;
    }
    __syncthreads();

    // combine: one (batch, hidden) element per thread
    float iv = glds[0][b_l][h_l], fv = glds[1][b_l][h_l];
    float gv = glds[2][b_l][h_l], ov = glds[3][b_l][h_l];
    float zv = 1.f/(1.f + __expf(-(zpc + zsum[b_l])));
    float ig = iv * gv;
    float cn = zv*ig + (1.f - zv)*(fv*c_reg + ig);
    float th = 2.f/(1.f + __expf(-2.f*cn)) - 1.f;
    float hv_ = ov * th;
    c_reg = cn;
    const int hoff = browg*1024 + hb*16 + h_l;
    hn[hoff] = f2b(hv_);
    __builtin_nontemporal_store(hv_, out + (size_t)t*65536 + hoff);
    if (t == NT-1){
      out[(size_t)NT*65536 + hoff] = hv_;            // hT
      out[(size_t)NT*65536 + 65536 + hoff] = cn;     // cT
    }
    group_barrier(cnt, gen, 64);
  }
}

// ---------------- host ----------------
extern "C" void kernel_launch(void* const* d_in, const int* in_sizes, int n_in,
                              void* d_out, int out_size, void* d_ws, size_t ws_size,
                              hipStream_t stream)
{
  (void)in_sizes; (void)n_in; (void)out_size;
  const float* x    = (const float*)d_in[0];
  const float* Wih  = (const float*)d_in[1];
  const float* Whh  = (const float*)d_in[2];
  const float* b_ih = (const float*)d_in[3];
  const float* b_hh = (const float*)d_in[4];
  float* out = (float*)d_out;

  size_t off = 0;
  auto alloc = [&](size_t bytes)->void*{
    void* p = (char*)d_ws + off;
    off = (off + bytes + 255) & ~(size_t)255;
    return p;
  };
  u16*  xb   = (u16*) alloc((size_t)NTB*1024*2);
  u16*  wihb = (u16*) alloc((size_t)4097*1024*2);
  u16*  whhb = (u16*) alloc((size_t)4097*1024*2);
  u16*  hb   = (u16*) alloc((size_t)2*65536*2);
  float* zp  = (float*)alloc((size_t)NTB*4);
  unsigned* bar = (unsigned*)alloc(4096);
  bool g32 = (ws_size >= off + (size_t)NTB*G4*4);
  void* gxp = (char*)d_ws + off;

  hipMemsetAsync(bar, 0, 4096, stream);
  cvt_bf16<<<dim3(2048), dim3(256), 0, stream>>>(x,   xb,   NTB*1024/8);
  cvt_bf16<<<dim3(512),  dim3(256), 0, stream>>>(Wih, wihb, 4097*1024/8);
  cvt_bf16<<<dim3(512),  dim3(256), 0, stream>>>(Whh, whhb, 4097*1024/8);
  zpre_kernel<<<dim3(256), dim3(256), 0, stream>>>(x, Wih, b_ih, b_hh, zp);
  if (g32){
    gemm_gx<float><<<dim3(8192), dim3(256), 0, stream>>>(xb, wihb, b_ih, b_hh, (float*)gxp);
    hmlstm_scan<float><<<dim3(256), dim3(256), 0, stream>>>(whhb, (const float*)gxp, zp,
                                                            hb, hb + 65536, out, bar);
  } else {
    gemm_gx<u16><<<dim3(8192), dim3(256), 0, stream>>>(xb, wihb, b_ih, b_hh, (u16*)gxp);
    hmlstm_scan<u16><<<dim3(256), dim3(256), 0, stream>>>(whhb, (const u16*)gxp, zp,
                                                          hb, hb + 65536, out, bar);
  }
}

// Round 2
// 3274.028 us; speedup vs baseline: 4.4466x; 4.4466x over previous
//
#include <hip/hip_runtime.h>
#include <cstdint>
#include <cstddef>

typedef unsigned short u16;
typedef short bf16x8 __attribute__((ext_vector_type(8)));
typedef u16   u16x8  __attribute__((ext_vector_type(8)));
typedef float f32x4  __attribute__((ext_vector_type(4)));

#define NT  512
#define NB  64
#define NH  1024
#define NTB 32768   // NT*NB
#define G4  4096

#define AS1C(p) ((const __attribute__((address_space(1))) void*)(p))
#define AS3(p)  ((__attribute__((address_space(3))) void*)(p))

__device__ __forceinline__ float b2f(u16 u){
  return __uint_as_float(((unsigned)u) << 16);
}
__device__ __forceinline__ u16 f2b(float f){
  unsigned u = __float_as_uint(f);
  return (u16)((u + 0x7fffu + ((u >> 16) & 1u)) >> 16);
}

// ---------------- f32 -> bf16 conversion ----------------
__global__ void cvt_bf16(const float* __restrict__ in, u16* __restrict__ out, int n8){
  int stride = gridDim.x * blockDim.x;
  for (int i = blockIdx.x * blockDim.x + threadIdx.x; i < n8; i += stride){
    const float4* p = (const float4*)(in + (size_t)i * 8);
    float4 a = p[0], b = p[1];
    u16x8 r;
    r[0]=f2b(a.x); r[1]=f2b(a.y); r[2]=f2b(a.z); r[3]=f2b(a.w);
    r[4]=f2b(b.x); r[5]=f2b(b.y); r[6]=f2b(b.z); r[7]=f2b(b.w);
    *(u16x8*)(out + (size_t)i * 8) = r;
  }
}

// ---------------- z-gate precompute: z_pre[r] = x[r,:] . W_ih[4096,:] + bias ----------------
__global__ void zpre_kernel(const float* __restrict__ x, const float* __restrict__ Wih,
                            const float* __restrict__ b_ih, const float* __restrict__ b_hh,
                            float* __restrict__ zp){
  int gw   = (blockIdx.x * 256 + threadIdx.x) >> 6;
  int lane = threadIdx.x & 63;
  const float* wz = Wih + (size_t)4096 * 1024;
  float4 wv[4];
  #pragma unroll
  for (int j = 0; j < 4; ++j) wv[j] = *(const float4*)&wz[lane*16 + j*4];
  float bz = b_ih[4096] + b_hh[4096];
  for (int r = gw; r < NTB; r += 1024){
    const float* xr = x + (size_t)r * 1024 + lane * 16;
    float s = 0.f;
    #pragma unroll
    for (int j = 0; j < 4; ++j){
      float4 xv = *(const float4*)&xr[j*4];
      s += xv.x*wv[j].x + xv.y*wv[j].y + xv.z*wv[j].z + xv.w*wv[j].w;
    }
    #pragma unroll
    for (int o = 32; o > 0; o >>= 1) s += __shfl_down(s, o);
    if (lane == 0) zp[r] = s + bz;
  }
}

// ---------------- Phase-1 GEMM: gx[32768,4096] = Xb @ Wb^T + bias ----------------
template<typename GT>
__global__ __launch_bounds__(256, 2) void gemm_gx(
    const u16* __restrict__ Xb, const u16* __restrict__ Wb,
    const float* __restrict__ b_ih, const float* __restrict__ b_hh,
    GT* __restrict__ gx)
{
  __shared__ u16 As[128*32];
  __shared__ u16 Bs[128*32];
  const int tid  = threadIdx.x;
  const int lane = tid & 63, wave = tid >> 6;
  const int wr = wave >> 1, wc = wave & 1;
  const int m0 = (blockIdx.x & 255) * 128;
  const int n0 = (blockIdx.x >> 8) * 128;
  const int srow = wave * 16 + (lane >> 2);
  const int scol = (lane & 3) * 8;
  const u16* gA = Xb + (size_t)(m0 + srow) * 1024 + scol;
  const u16* gB = Wb + (size_t)(n0 + srow) * 1024 + scol;
  char* lA = (char*)As + wave * 1024;
  char* lB = (char*)Bs + wave * 1024;
  const int fr = lane & 15, fo = (lane >> 4) * 8;

  f32x4 acc[4][4] = {};
  for (int k0 = 0; k0 < 1024; k0 += 32){
    __syncthreads();
    __builtin_amdgcn_global_load_lds(AS1C(gA + k0),            AS3(lA),        16, 0, 0);
    __builtin_amdgcn_global_load_lds(AS1C(gA + 64*1024 + k0),  AS3(lA + 4096), 16, 0, 0);
    __builtin_amdgcn_global_load_lds(AS1C(gB + k0),            AS3(lB),        16, 0, 0);
    __builtin_amdgcn_global_load_lds(AS1C(gB + 64*1024 + k0),  AS3(lB + 4096), 16, 0, 0);
    __syncthreads();
    bf16x8 a[4], b[4];
    #pragma unroll
    for (int mi = 0; mi < 4; ++mi)
      a[mi] = *(const bf16x8*)&As[(wr*64 + mi*16 + fr)*32 + fo];
    #pragma unroll
    for (int ni = 0; ni < 4; ++ni)
      b[ni] = *(const bf16x8*)&Bs[(wc*64 + ni*16 + fr)*32 + fo];
    #pragma unroll
    for (int mi = 0; mi < 4; ++mi)
      #pragma unroll
      for (int ni = 0; ni < 4; ++ni)
        acc[mi][ni] = __builtin_amdgcn_mfma_f32_16x16x32_bf16(a[mi], b[ni], acc[mi][ni], 0, 0, 0);
  }
  const int orow = (lane >> 4) * 4, ocol = lane & 15;
  #pragma unroll
  for (int ni = 0; ni < 4; ++ni){
    const int g = n0 + wc*64 + ni*16 + ocol;
    const float bias = b_ih[g] + b_hh[g];
    #pragma unroll
    for (int mi = 0; mi < 4; ++mi){
      const size_t rb = (size_t)(m0 + wr*64 + mi*16 + orow);
      #pragma unroll
      for (int r = 0; r < 4; ++r){
        float v = acc[mi][ni][r] + bias;
        if constexpr (sizeof(GT) == 4)
          __builtin_nontemporal_store(v, (float*)gx + (rb + r)*G4 + g);
        else
          __builtin_nontemporal_store(f2b(v), (u16*)gx + (rb + r)*G4 + g);
      }
    }
  }
}

__device__ __forceinline__ float ld_gx(const float* p){ return __builtin_nontemporal_load(p); }
__device__ __forceinline__ float ld_gx(const u16* p){ return b2f(__builtin_nontemporal_load(p)); }

// ---------------- Phase-2 persistent scan ----------------
// 256 WGs x 256 thr. WG = (mb: batch-group of 16, hb: 16 hidden units).
// Wave w owns gate w; its W_hh slice lives in VGPRs (Bw[32], pinned).
// h exchange via L3 (sc0 sc1 bypass loads/stores) + per-WG flag array: no
// atomics, no fences, no L2 flush.
template<typename GT>
__global__ __launch_bounds__(256, 1) void hmlstm_scan(
    const u16* __restrict__ Whh, const GT* __restrict__ gx,
    const float* __restrict__ zpre, u16* __restrict__ h0, u16* __restrict__ h1,
    float* __restrict__ out, unsigned* __restrict__ bar)
{
  const int tid  = threadIdx.x;
  const int lane = tid & 63, wave = tid >> 6;
  const int wg = blockIdx.x;
  const int mb = wg >> 6, hb = wg & 63;
  const int fr = lane & 15, hi4 = lane >> 4;
  const int b_l = tid >> 4, h_l = tid & 15;      // combine mapping: 16x16 = 256 threads
  const int browg = mb*16 + b_l;

  __shared__ u16  hs[16*1024];       // 32KB, XOR-swizzled h tile of this batch-group
  __shared__ float glds[4][16][16];
  __shared__ float zpart[4][16];
  __shared__ u16  wz[1024];

  ((unsigned long long*)wz)[tid] = ((const unsigned long long*)(Whh + (size_t)4096*1024))[tid];

  // persistent W_hh fragments: gate row = wave*1024 + hb*16 + fr
  const int grow = wave*1024 + hb*16 + fr;
  bf16x8 Bw[32];
  #pragma unroll
  for (int kc = 0; kc < 32; ++kc)
    Bw[kc] = *(const bf16x8*)&Whh[(size_t)grow*1024 + kc*32 + hi4*8];
  #pragma unroll
  for (int kc = 0; kc < 32; ++kc)
    asm volatile("" : "+v"(Bw[kc]));   // pin in VGPRs (forbid remat)

  // zero h^0 through L3 so sc1 readers see it
  {
    u16* p = h0 + (size_t)mb*16384 + hb*256 + tid;
    unsigned z = 0;
    asm volatile("global_store_short %0, %1, off sc0 sc1" :: "v"(p), "v"(z) : "memory");
    asm volatile("s_waitcnt vmcnt(0)" ::: "memory");
  }
  __syncthreads();
  unsigned* myflag = bar + mb*64 + hb;
  const unsigned* gflags = bar + mb*64;
  if (tid == 0){
    unsigned one = 1;
    asm volatile("global_store_dword %0, %1, off sc0 sc1" :: "v"(myflag), "v"(one) : "memory");
  }

  float c_reg = 0.f;

  for (int t = 0; t < NT; ++t){
    const u16* hc = (t & 1) ? h1 : h0;
    u16*       hn = (t & 1) ? h0 : h1;

    // prefetch gx + zpre (cached, nt) — independent of h, hide under spin
    float gxl[4];
    const GT* gp = gx + ((size_t)t*64 + mb*16 + hi4*4)*G4 + wave*1024 + hb*16 + fr;
    #pragma unroll
    for (int r = 0; r < 4; ++r) gxl[r] = ld_gx(gp + (size_t)r*G4);
    float zpc = zpre[t*64 + browg];

    // acquire: all 64 WGs of this group have published h^t (flag >= t+1)
    {
      const unsigned* fp = gflags + lane;
      unsigned fv, tgt = (unsigned)(t + 1);
      do {
        asm volatile("global_load_dword %0, %1, off sc0 sc1\n\ts_waitcnt vmcnt(0)"
                     : "=v"(fv) : "v"(fp) : "memory");
      } while (!__all((int)(fv >= tgt)));
      __builtin_amdgcn_sched_barrier(0);
    }

    // stage h^t tile (16 x 1024 bf16) global->LDS, swizzled
    uint4 sv[8];
    #pragma unroll
    for (int j = 0; j < 8; ++j){
      int idx = tid + j*256;
      int row = idx >> 7, cc = idx & 127;
      const u16* src = hc + (size_t)(mb*16 + row)*1024 + cc*8;
      asm volatile("global_load_dwordx4 %0, %1, off sc0 sc1" : "=v"(sv[j]) : "v"(src) : "memory");
    }
    asm volatile("s_waitcnt vmcnt(0)" ::: "memory");
    __builtin_amdgcn_sched_barrier(0);
    #pragma unroll
    for (int j = 0; j < 8; ++j){
      int idx = tid + j*256;
      int row = idx >> 7, cc = idx & 127;
      *(uint4*)((char*)hs + row*2048 + ((cc*16) ^ ((row&7)<<4))) = sv[j];
    }
    __syncthreads();

    // recurrent GEMM: 16 batches x 16 gate cols, K=1024, A from LDS (swizzled)
    f32x4 acc[4] = {}, az = {};
    #pragma unroll
    for (int kc = 0; kc < 32; ++kc){
      bf16x8 a = *(const bf16x8*)((char*)hs + fr*2048 + ((kc*64 + hi4*16) ^ ((fr&7)<<4)));
      acc[kc & 3] = __builtin_amdgcn_mfma_f32_16x16x32_bf16(a, Bw[kc], acc[kc & 3], 0, 0, 0);
    }
    // z-gate MFMA: wave w covers kc in [w*8, w*8+8), B = broadcast W_z row
    #pragma unroll
    for (int q = 0; q < 8; ++q){
      int kcz = wave*8 + q;
      bf16x8 a  = *(const bf16x8*)((char*)hs + fr*2048 + ((kcz*64 + hi4*16) ^ ((fr&7)<<4)));
      bf16x8 bz = *(const bf16x8*)&wz[kcz*32 + hi4*8];
      az = __builtin_amdgcn_mfma_f32_16x16x32_bf16(a, bz, az, 0, 0, 0);
    }
    f32x4 ac = (acc[0] + acc[1]) + (acc[2] + acc[3]);

    // gates -> LDS (wave 2 = tanh, others sigmoid)
    #pragma unroll
    for (int r = 0; r < 4; ++r){
      float v = ac[r] + gxl[r];
      float s = (wave == 2) ? (2.f/(1.f + __expf(-2.f*v)) - 1.f)
                            : (1.f/(1.f + __expf(-v)));
      glds[wave][hi4*4 + r][fr] = s;
    }
    if (fr == 0){
      #pragma unroll
      for (int r = 0; r < 4; ++r) zpart[wave][hi4*4 + r] = az[r];
    }
    __syncthreads();

    // combine: one (batch, hidden) element per thread
    float iv = glds[0][b_l][h_l], fvg = glds[1][b_l][h_l];
    float gv = glds[2][b_l][h_l], ov = glds[3][b_l][h_l];
    float zs = zpart[0][b_l] + zpart[1][b_l] + zpart[2][b_l] + zpart[3][b_l];
    float zv = 1.f/(1.f + __expf(-(zpc + zs)));
    float ig = iv * gv;
    float cn = zv*ig + (1.f - zv)*(fvg*c_reg + ig);
    float th = 2.f/(1.f + __expf(-2.f*cn)) - 1.f;
    float hv_ = ov * th;
    c_reg = cn;
    const int hoff = browg*1024 + hb*16 + h_l;
    {
      unsigned hv16 = (unsigned)f2b(hv_);
      asm volatile("global_store_short %0, %1, off sc0 sc1" :: "v"(hn + hoff), "v"(hv16) : "memory");
    }
    __builtin_nontemporal_store(hv_, out + (size_t)t*65536 + hoff);
    if (t == NT-1){
      out[(size_t)NT*65536 + hoff] = hv_;            // hT
      out[(size_t)NT*65536 + 65536 + hoff] = cn;     // cT
    }
    // release: h stores visible in L3, then publish flag = t+2
    asm volatile("s_waitcnt vmcnt(0)" ::: "memory");
    __syncthreads();
    if (tid == 0){
      unsigned pv = (unsigned)(t + 2);
      asm volatile("global_store_dword %0, %1, off sc0 sc1" :: "v"(myflag), "v"(pv) : "memory");
    }
  }
}

// ---------------- host ----------------
extern "C" void kernel_launch(void* const* d_in, const int* in_sizes, int n_in,
                              void* d_out, int out_size, void* d_ws, size_t ws_size,
                              hipStream_t stream)
{
  (void)in_sizes; (void)n_in; (void)out_size;
  const float* x    = (const float*)d_in[0];
  const float* Wih  = (const float*)d_in[1];
  const float* Whh  = (const float*)d_in[2];
  const float* b_ih = (const float*)d_in[3];
  const float* b_hh = (const float*)d_in[4];
  float* out = (float*)d_out;

  size_t off = 0;
  auto alloc = [&](size_t bytes)->void*{
    void* p = (char*)d_ws + off;
    off = (off + bytes + 255) & ~(size_t)255;
    return p;
  };
  u16*  xb   = (u16*) alloc((size_t)NTB*1024*2);
  u16*  wihb = (u16*) alloc((size_t)4097*1024*2);
  u16*  whhb = (u16*) alloc((size_t)4097*1024*2);
  u16*  hb   = (u16*) alloc((size_t)2*65536*2);
  float* zp  = (float*)alloc((size_t)NTB*4);
  unsigned* bar = (unsigned*)alloc(4096);
  bool g32 = (ws_size >= off + (size_t)NTB*G4*4);
  void* gxp = (char*)d_ws + off;

  hipMemsetAsync(bar, 0, 4096, stream);
  cvt_bf16<<<dim3(2048), dim3(256), 0, stream>>>(x,   xb,   NTB*1024/8);
  cvt_bf16<<<dim3(512),  dim3(256), 0, stream>>>(Wih, wihb, 4097*1024/8);
  cvt_bf16<<<dim3(512),  dim3(256), 0, stream>>>(Whh, whhb, 4097*1024/8);
  zpre_kernel<<<dim3(256), dim3(256), 0, stream>>>(x, Wih, b_ih, b_hh, zp);
  if (g32){
    gemm_gx<float><<<dim3(8192), dim3(256), 0, stream>>>(xb, wihb, b_ih, b_hh, (float*)gxp);
    hmlstm_scan<float><<<dim3(256), dim3(256), 0, stream>>>(whhb, (const float*)gxp, zp,
                                                            hb, hb + 65536, out, bar);
  } else {
    gemm_gx<u16><<<dim3(8192), dim3(256), 0, stream>>>(xb, wihb, b_ih, b_hh, (u16*)gxp);
    hmlstm_scan<u16><<<dim3(256), dim3(256), 0, stream>>>(whhb, (const u16*)gxp, zp,
                                                          hb, hb + 65536, out, bar);
  }
}